// Round 7
// baseline (886.671 us; speedup 1.0000x reference)
//
#include <hip/hip_runtime.h>
#include <hip/hip_bf16.h>

#define RR 7
#define EPSBN 1e-5f

typedef __attribute__((ext_vector_type(8))) __bf16 bf16x8;
typedef __attribute__((ext_vector_type(4))) float f32x4;
typedef __attribute__((ext_vector_type(2))) float f32x2;

__device__ __forceinline__ float uhi2f(unsigned int u) {
    union { unsigned int i; float f; } c; c.i = u; return c.f;
}
__device__ __forceinline__ unsigned short f2b(float f) {
    union { float f; unsigned int i; } c; c.f = f;
    unsigned int x = c.i;
    return (unsigned short)((x + 0x7fffu + ((x >> 16) & 1u)) >> 16);
}

// ---------------- CSR build ----------------
__global__ void hist_k(const int* __restrict__ dst, const int* __restrict__ et,
                       int* __restrict__ cnt, int ne) {
    int e = blockIdx.x * 256 + threadIdx.x;
    if (e < ne) atomicAdd(&cnt[dst[e] * RR + et[e]], 1);
}
__global__ void scan1_k(const int* __restrict__ cnt, int* __restrict__ bsum, int n) {
    __shared__ int sh[256];
    int base = blockIdx.x << 10;
    int s = 0;
    for (int i = threadIdx.x; i < 1024; i += 256) { int idx = base + i; if (idx < n) s += cnt[idx]; }
    sh[threadIdx.x] = s; __syncthreads();
    for (int off = 128; off > 0; off >>= 1) {
        if (threadIdx.x < off) sh[threadIdx.x] += sh[threadIdx.x + off];
        __syncthreads();
    }
    if (threadIdx.x == 0) bsum[blockIdx.x] = sh[0];
}
__global__ void scan2_k(int* __restrict__ bsum, int nb) {   // nb <= 1024
    __shared__ int sh[256];
    int t = threadIdx.x;
    int v[4]; int loc = 0;
#pragma unroll
    for (int i = 0; i < 4; ++i) { int idx = t * 4 + i; v[i] = (idx < nb) ? bsum[idx] : 0; loc += v[i]; }
    sh[t] = loc; __syncthreads();
    for (int off = 1; off < 256; off <<= 1) {
        int x = (t >= off) ? sh[t - off] : 0;
        __syncthreads();
        sh[t] += x;
        __syncthreads();
    }
    int ex = (t > 0) ? sh[t - 1] : 0;
#pragma unroll
    for (int i = 0; i < 4; ++i) { int idx = t * 4 + i; if (idx < nb) { int vv = v[i]; bsum[idx] = ex; ex += vv; } }
}
__global__ void scan3_k(const int* __restrict__ cnt, const int* __restrict__ boff,
                        int* __restrict__ ptr, int* __restrict__ cursor, int n, int total) {
    __shared__ int sh[256];
    int t = threadIdx.x;
    int base = (blockIdx.x << 10) + (t << 2);
    int v[4]; int loc = 0;
#pragma unroll
    for (int i = 0; i < 4; ++i) { int idx = base + i; v[i] = (idx < n) ? cnt[idx] : 0; loc += v[i]; }
    sh[t] = loc; __syncthreads();
    for (int off = 1; off < 256; off <<= 1) {
        int x = (t >= off) ? sh[t - off] : 0;
        __syncthreads();
        sh[t] += x;
        __syncthreads();
    }
    int ex = boff[blockIdx.x] + ((t > 0) ? sh[t - 1] : 0);
#pragma unroll
    for (int i = 0; i < 4; ++i) {
        int idx = base + i;
        if (idx < n) { ptr[idx] = ex; cursor[idx] = ex; ex += v[i]; }
    }
    if (blockIdx.x == 0 && t == 0) ptr[n] = total;
}
__global__ void scatter_k(const int* __restrict__ src, const int* __restrict__ dst,
                          const int* __restrict__ et, int* __restrict__ cursor,
                          int* __restrict__ ssorted, int ne) {
    int e = blockIdx.x * 256 + threadIdx.x;
    if (e < ne) {
        int seg = dst[e] * RR + et[e];
        int pos = atomicAdd(&cursor[seg], 1);
        ssorted[pos] = src[e];
    }
}

// ---------------- fused prep: weights + features + fc transposes + BN fold ----------------
// roles by blockIdx: [0,24) wall; [24,24+nhb) h; [.., +256) w0t; [.., +128) w1t; last AB
__global__ __launch_bounds__(256) void prep_all_k(
    const float* __restrict__ rel_w, const float* __restrict__ root_w,
    unsigned short* __restrict__ wall,
    const int* __restrict__ x, const float* __restrict__ embed,
    unsigned short* __restrict__ h, int n, int nhb,
    const float* __restrict__ fc0w, const float* __restrict__ fc1w,
    float* __restrict__ w0t, float* __restrict__ w1t,
    const float* __restrict__ conv_b,
    const float* __restrict__ bn_g, const float* __restrict__ bn_b,
    const float* __restrict__ bn_m, const float* __restrict__ bn_v,
    float* __restrict__ AB)
{
    __shared__ unsigned short T[128][130];
    int b = blockIdx.x;
    int t = threadIdx.x;
    if (b < 24) {
        // wall: [l*8+kb][frag=ks*8+nt][lane][j], element = W[i][o]
        int l = b >> 3, kb = b & 7;
        const float* src = (kb < RR) ? rel_w + ((size_t)(l * RR + kb) << 14)
                                     : root_w + ((size_t)l << 14);
        for (int c = t; c < 4096; c += 256) {
            float4 f = *(const float4*)(src + (c << 2));
            int i = c >> 5, o = (c & 31) << 2;
            T[i][o] = f2b(f.x); T[i][o+1] = f2b(f.y); T[i][o+2] = f2b(f.z); T[i][o+3] = f2b(f.w);
        }
        __syncthreads();
        unsigned short* dst = wall + ((size_t)b << 14);
        for (int c = t; c < 2048; c += 256) {
            int frag = c >> 6;
            int lane = c & 63;
            int ks = frag >> 3, nt = frag & 7;
            int o = (nt << 4) + (lane & 15);
            int ib = (ks << 5) + ((lane >> 4) << 3);
            uint4 o4;
            o4.x = (unsigned)T[ib+0][o] | ((unsigned)T[ib+1][o] << 16);
            o4.y = (unsigned)T[ib+2][o] | ((unsigned)T[ib+3][o] << 16);
            o4.z = (unsigned)T[ib+4][o] | ((unsigned)T[ib+5][o] << 16);
            o4.w = (unsigned)T[ib+6][o] | ((unsigned)T[ib+7][o] << 16);
            *(uint4*)(dst + (c << 3)) = o4;
        }
    } else if (b < 24 + nhb) {
        int i = (b - 24) * 256 + t;
        if (i < n * 16) {
            int node = i >> 4, c8 = (i & 15) << 3;
            const float* e = embed + ((size_t)x[node] << 7) + c8;
            float4 f0 = *(const float4*)e;
            float4 f1 = *(const float4*)(e + 4);
            uint4 o4;
            o4.x = (unsigned)f2b(f0.x) | ((unsigned)f2b(f0.y) << 16);
            o4.y = (unsigned)f2b(f0.z) | ((unsigned)f2b(f0.w) << 16);
            o4.z = (unsigned)f2b(f1.x) | ((unsigned)f2b(f1.y) << 16);
            o4.w = (unsigned)f2b(f1.z) | ((unsigned)f2b(f1.w) << 16);
            *(uint4*)(h + ((size_t)node << 7) + c8) = o4;
        }
    } else if (b < 24 + nhb + 256) {
        int idx = ((b - 24 - nhb) << 8) + t;
        int o = idx & 255, i = idx >> 8;
        w0t[idx] = fc0w[o * 256 + i];
    } else if (b < 24 + nhb + 384) {
        int idx = ((b - 24 - nhb - 256) << 8) + t;
        int o = idx & 127, i = idx >> 7;
        w1t[idx] = fc1w[o * 256 + i];
    } else {
        for (int q = t; q < 384; q += 256) {
            int l = q >> 7, j = q & 127;
            float A = 1.f, Bv = conv_b[(l << 7) + j];
            if (l < 2) {
                float sc = bn_g[(l << 7) + j] * rsqrtf(bn_v[(l << 7) + j] + EPSBN);
                A = sc;
                Bv = Bv * sc + (bn_b[(l << 7) + j] - bn_m[(l << 7) + j] * sc);
            }
            AB[(l << 8) + j] = A;
            AB[(l << 8) + 128 + j] = Bv;
        }
    }
}

#define PAIRF(w) ((f32x2){uhi2f((w) << 16), uhi2f((w) & 0xffff0000u)})
#define ACCP(b, u) { av2[(b)+0] += PAIRF((u).x); av2[(b)+1] += PAIRF((u).y); \
                     av2[(b)+2] += PAIRF((u).z); av2[(b)+3] += PAIRF((u).w); }
#define GATH(s) { const unsigned short* hp = h_in + ((size_t)(s) << 7) + (quad << 3); \
                  uint4 u0 = *(const uint4*)(hp);       uint4 u1 = *(const uint4*)(hp + 32); \
                  uint4 u2 = *(const uint4*)(hp + 64);  uint4 u3 = *(const uint4*)(hp + 96); \
                  ACCP(0, u0); ACCP(4, u1); ACCP(8, u2); ACCP(12, u3); }
#define LOAD4(dst, s) { const unsigned short* hp = h_in + ((size_t)(s) << 7) + (quad << 3); \
                  (dst)[0] = *(const uint4*)(hp);      (dst)[1] = *(const uint4*)(hp + 32); \
                  (dst)[2] = *(const uint4*)(hp + 64); (dst)[3] = *(const uint4*)(hp + 96); }

// ---------------- fused RGCN layer: batched 16-load staging per relation ----------------
// All (up to) 4 rows' loads of a relation issued in one region into u[16], accumulation
// after — maximizes loads in flight per phase. __launch_bounds__(256,3): 170-reg budget
// so the compiler does not serialize staging (round-6's 64-VGPR throttle).
__global__ __launch_bounds__(256, 3) void layer_k(
    const unsigned short* __restrict__ h_in,   // bf16 [N][128]
    unsigned short* __restrict__ h_out,        // bf16 [nout][128]
    const unsigned short* __restrict__ wfrag,  // bf16 [8][32][512]
    const float* __restrict__ AB,              // [2][128] scale,shift
    const int* __restrict__ seg_ptr, const int* __restrict__ src_sorted,
    const int* __restrict__ list_a, const int* __restrict__ list_b, int listB,
    int nout, int bnrelu)
{
    const int tid  = threadIdx.x;
    const int wave = tid >> 6;
    const int lane = tid & 63;
    const int n16  = lane & 15;
    const int quad = lane >> 4;
    const int row0 = blockIdx.x << 6;
    const int gidx = row0 + (wave << 4) + n16;   // output row
    const bool valid = gidx < nout;
    int gnode = 0;
    if (valid) {
        gnode = list_a ? (gidx < listB ? list_a[gidx] : list_b[gidx - listB]) : gidx;
    }

    int p[8];
    {
        int b = valid ? gnode * RR : 0;
#pragma unroll
        for (int i = 0; i < 8; ++i) p[i] = seg_ptr[b + i];
    }

    f32x4 acc[8];
#pragma unroll
    for (int i = 0; i < 8; ++i) acc[i] = (f32x4){0.f, 0.f, 0.f, 0.f};

    const unsigned short* wl = wfrag + (lane << 3);

#pragma unroll
    for (int kb = 0; kb < 8; ++kb) {
        f32x2 av2[16];
#pragma unroll
        for (int i = 0; i < 16; ++i) av2[i] = (f32x2){0.f, 0.f};
        float scale = 1.f;
        if (kb < RR) {
            int e0 = p[kb], e1 = p[kb + 1];
            int cnt = valid ? (e1 - e0) : 0;
            if (cnt > 0) scale = __builtin_amdgcn_rcpf((float)cnt);
            // index loads (src_sorted padded >=16 ints past E)
            int s0 = src_sorted[e0];
            int s1 = src_sorted[e0 + 1];
            int s2 = src_sorted[e0 + 2];
            int s3 = src_sorted[e0 + 3];
            // ---- batched load region: up to 16 loads in flight ----
            uint4 u[16];
            if (cnt > 0) LOAD4(u + 0,  s0);
            if (cnt > 1) LOAD4(u + 4,  s1);
            if (cnt > 2) LOAD4(u + 8,  s2);
            if (cnt > 3) LOAD4(u + 12, s3);
            // ---- accumulate region ----
            if (cnt > 0) { ACCP(0, u[0]);  ACCP(4, u[1]);  ACCP(8, u[2]);  ACCP(12, u[3]);  }
            if (cnt > 1) { ACCP(0, u[4]);  ACCP(4, u[5]);  ACCP(8, u[6]);  ACCP(12, u[7]);  }
            if (cnt > 2) { ACCP(0, u[8]);  ACCP(4, u[9]);  ACCP(8, u[10]); ACCP(12, u[11]); }
            if (cnt > 3) { ACCP(0, u[12]); ACCP(4, u[13]); ACCP(8, u[14]); ACCP(12, u[15]); }
            for (int e = e0 + 4; e < e0 + cnt; ++e) {
                int s = src_sorted[e];
                GATH(s);
            }
        } else {
            if (valid) GATH(gnode);
        }
        // convert to bf16 A-fragments
        uint4 au[4];
#pragma unroll
        for (int ks = 0; ks < 4; ++ks) {
            unsigned pw[4];
#pragma unroll
            for (int m = 0; m < 4; ++m) {
                f32x2 q = av2[(ks << 2) + m] * scale;
                __hip_bfloat162 b2 = __float22bfloat162_rn(make_float2(q.x, q.y));
                unsigned uu; __builtin_memcpy(&uu, &b2, 4);
                pw[m] = uu;
            }
            au[ks].x = pw[0]; au[ks].y = pw[1]; au[ks].z = pw[2]; au[ks].w = pw[3];
        }
        // MFMA, B-fragments from global (L2-resident 32KB)
        const unsigned short* wk = wl + (kb << 14);
#pragma unroll
        for (int ks = 0; ks < 4; ++ks) {
            bf16x8 af;
            __builtin_memcpy(&af, &au[ks], 16);
#pragma unroll
            for (int nt = 0; nt < 8; ++nt) {
                bf16x8 bfr = *(const bf16x8*)(wk + (((ks << 3) + nt) << 9));
                acc[nt] = __builtin_amdgcn_mfma_f32_16x16x32_bf16(af, bfr, acc[nt], 0, 0, 0);
            }
        }
    }

    // epilogue: v = acc*A + B (BN+bias folded), ReLU, store bf16
    // C/D layout: col = lane&15, row = (lane>>4)*4 + reg
#pragma unroll
    for (int nt = 0; nt < 8; ++nt) {
        int j = (nt << 4) + n16;
        float Aj = AB[j];
        float Bj = AB[128 + j];
#pragma unroll
        for (int r = 0; r < 4; ++r) {
            int orow = row0 + (wave << 4) + (quad << 2) + r;
            if (orow < nout) {
                float v = acc[nt][r] * Aj + Bj;
                if (bnrelu) v = fmaxf(v, 0.f);
                h_out[((size_t)orow << 7) + j] = f2b(v);
            }
        }
    }
}

// ---------------- MLP head: 16 rows/block; transposed weights, coalesced ----------------
__global__ __launch_bounds__(256) void mlp_k(
    const unsigned short* __restrict__ hC,     // compact [2B][128]
    const float* __restrict__ w0t, const float* __restrict__ bb0,   // w0t [256 in][256 out]
    const float* __restrict__ w1t, const float* __restrict__ bb1,   // w1t [256 in][128 out]
    const float* __restrict__ w2, const float* __restrict__ bb2,
    float* __restrict__ out, int Bn)
{
    __shared__ __attribute__((aligned(16))) float g0[16][256];
    __shared__ __attribute__((aligned(16))) float g1[16][256];
    __shared__ float lg[16][4];
    int t = threadIdx.x;
    {
        int row = t >> 4;
        int cseg = (t & 15) << 4;
        int gr = (blockIdx.x << 4) + row;
        int gc = (gr < Bn) ? gr : 0;
        const unsigned short* sp = (cseg < 128) ? (hC + ((size_t)gc << 7) + cseg)
                                                : (hC + ((size_t)(Bn + gc) << 7) + (cseg - 128));
#pragma unroll
        for (int c8 = 0; c8 < 2; ++c8) {
            uint4 v = *(const uint4*)(sp + (c8 << 3));
            int base = cseg + (c8 << 3);
            g0[row][base+0] = uhi2f(v.x << 16); g0[row][base+1] = uhi2f(v.x & 0xffff0000u);
            g0[row][base+2] = uhi2f(v.y << 16); g0[row][base+3] = uhi2f(v.y & 0xffff0000u);
            g0[row][base+4] = uhi2f(v.z << 16); g0[row][base+5] = uhi2f(v.z & 0xffff0000u);
            g0[row][base+6] = uhi2f(v.w << 16); g0[row][base+7] = uhi2f(v.w & 0xffff0000u);
        }
    }
    __syncthreads();
    {   // fc0: lane t = output col; w reads coalesced, g0 reads are LDS broadcasts
        float acc[16];
#pragma unroll
        for (int r = 0; r < 16; ++r) acc[r] = 0.f;
#pragma unroll 4
        for (int i = 0; i < 256; ++i) {
            float w = w0t[(i << 8) + t];
#pragma unroll
            for (int r = 0; r < 16; ++r) acc[r] += w * g0[r][i];
        }
        float bb = bb0[t];
#pragma unroll
        for (int r = 0; r < 16; ++r) g1[r][t] = fmaxf(acc[r] + bb, 0.f);
    }
    __syncthreads();
    {   // fc1: 128 outs x 2 row-groups
        int o = t & 127, rg = t >> 7;
        float acc[8];
#pragma unroll
        for (int r = 0; r < 8; ++r) acc[r] = 0.f;
#pragma unroll 4
        for (int i = 0; i < 256; ++i) {
            float w = w1t[(i << 7) + o];
#pragma unroll
            for (int r = 0; r < 8; ++r) acc[r] += w * g1[(rg << 3) + r][i];
        }
        float bb = bb1[o];
#pragma unroll
        for (int r = 0; r < 8; ++r) g0[(rg << 3) + r][o] = fmaxf(acc[r] + bb, 0.f);
    }
    __syncthreads();
    if (t < 48) {   // fc2
        int row = t / 3, cls = t - row * 3;
        const float* wr = w2 + (cls << 7);
        float a = 0.f;
        for (int i = 0; i < 128; i += 4) {
            float4 w = *(const float4*)(wr + i);
            float4 g = *(const float4*)&g0[row][i];
            a += w.x * g.x + w.y * g.y + w.z * g.z + w.w * g.w;
        }
        lg[row][cls] = a + bb2[cls];
    }
    __syncthreads();
    if (t < 16) {   // log_softmax + store
        int gr = (blockIdx.x << 4) + t;
        if (gr < Bn) {
            float l0 = lg[t][0], l1 = lg[t][1], l2 = lg[t][2];
            float m = fmaxf(l0, fmaxf(l1, l2));
            float lse = m + logf(expf(l0 - m) + expf(l1 - m) + expf(l2 - m));
            out[gr * 3 + 0] = l0 - lse;
            out[gr * 3 + 1] = l1 - lse;
            out[gr * 3 + 2] = l2 - lse;
        }
    }
}

extern "C" void kernel_launch(void* const* d_in, const int* in_sizes, int n_in,
                              void* d_out, int out_size, void* d_ws, size_t ws_size,
                              hipStream_t stream) {
    const int*   x      = (const int*)d_in[0];
    const int*   eidx   = (const int*)d_in[1];   // [2, E]
    const int*   etype  = (const int*)d_in[2];
    const int*   home   = (const int*)d_in[3];
    const int*   away   = (const int*)d_in[4];
    const float* embed  = (const float*)d_in[5];
    const float* rel_w  = (const float*)d_in[6];
    const float* root_w = (const float*)d_in[7];
    const float* conv_b = (const float*)d_in[8];
    const float* bn_g   = (const float*)d_in[9];
    const float* bn_b   = (const float*)d_in[10];
    const float* bn_m   = (const float*)d_in[11];
    const float* bn_v   = (const float*)d_in[12];
    const float* fc0w   = (const float*)d_in[13];
    const float* fc0b   = (const float*)d_in[14];
    const float* fc1w   = (const float*)d_in[15];
    const float* fc1b   = (const float*)d_in[16];
    const float* fc2w   = (const float*)d_in[17];
    const float* fc2b   = (const float*)d_in[18];
    float* out = (float*)d_out;

    const int N_ = in_sizes[0];
    const int E_ = in_sizes[2];
    const int B_ = in_sizes[3];
    const int NS = N_ * RR;

    char* ws = (char*)d_ws;
    auto alloc = [&](size_t bytes) -> char* {
        char* p = ws;
        ws += (bytes + 255) & ~(size_t)255;
        return p;
    };
    int* ptr         = (int*)alloc((size_t)(NS + 1) * 4);
    int* cursor      = (int*)alloc((size_t)NS * 4);
    int* bsum        = (int*)alloc(4096);
    int* src_sorted  = (int*)alloc((size_t)(E_ + 16) * 4);   // padded for batched loads
    unsigned short* wall = (unsigned short*)alloc((size_t)3 * 8 * 16384 * 2);
    unsigned short* hA   = (unsigned short*)alloc((size_t)N_ * 128 * 2);
    unsigned short* hB   = (unsigned short*)alloc((size_t)N_ * 128 * 2);
    unsigned short* hC   = (unsigned short*)alloc((size_t)2 * B_ * 128 * 2);
    float* AB        = (float*)alloc(3 * 256 * 4);
    float* w0t       = (float*)alloc(65536 * 4);
    float* w1t       = (float*)alloc(32768 * 4);

    const int nb = (NS + 1023) / 1024;
    const int nhb = (N_ * 16 + 255) / 256;

    // CSR build (segments constant across layers)
    (void)hipMemsetAsync(cursor, 0, (size_t)NS * 4, stream);
    hist_k<<<(E_ + 255) / 256, 256, 0, stream>>>(eidx + E_, etype, cursor, E_);
    scan1_k<<<nb, 256, 0, stream>>>(cursor, bsum, NS);
    scan2_k<<<1, 256, 0, stream>>>(bsum, nb);
    scan3_k<<<nb, 256, 0, stream>>>(cursor, bsum, ptr, cursor, NS, E_);
    scatter_k<<<(E_ + 255) / 256, 256, 0, stream>>>(eidx, eidx + E_, etype, cursor, src_sorted, E_);

    // fused prep: wall + hA + w0t/w1t transposes + AB
    prep_all_k<<<24 + nhb + 384 + 1, 256, 0, stream>>>(
        rel_w, root_w, wall, x, embed, hA, N_, nhb,
        fc0w, fc1w, w0t, w1t, conv_b, bn_g, bn_b, bn_m, bn_v, AB);

    const int lgrid = (N_ + 63) / 64;
    layer_k<<<lgrid, 256, 0, stream>>>(hA, hB, wall + 0 * 8 * 16384, AB + 0,
                                       ptr, src_sorted, nullptr, nullptr, 0, N_, 1);
    layer_k<<<lgrid, 256, 0, stream>>>(hB, hA, wall + 1 * 8 * 16384, AB + 256,
                                       ptr, src_sorted, nullptr, nullptr, 0, N_, 1);
    // layer 3: only home|away rows, compact output
    const int n3 = 2 * B_;
    layer_k<<<(n3 + 63) / 64, 256, 0, stream>>>(hA, hC, wall + 2 * 8 * 16384, AB + 512,
                                                ptr, src_sorted, home, away, B_, n3, 0);

    mlp_k<<<(B_ + 15) / 16, 256, 0, stream>>>(hC, w0t, fc0b, w1t, fc1b,
                                              fc2w, fc2b, out, B_);
}

// Round 9
// 686.246 us; speedup vs baseline: 1.2921x; 1.2921x over previous
//
#include <hip/hip_runtime.h>
#include <hip/hip_bf16.h>

#define RR 7
#define EPSBN 1e-5f

typedef __attribute__((ext_vector_type(8))) __bf16 bf16x8;
typedef __attribute__((ext_vector_type(4))) float f32x4;
typedef __attribute__((ext_vector_type(2))) float f32x2;

__device__ __forceinline__ float uhi2f(unsigned int u) {
    union { unsigned int i; float f; } c; c.i = u; return c.f;
}
__device__ __forceinline__ unsigned short f2b(float f) {
    union { float f; unsigned int i; } c; c.f = f;
    unsigned int x = c.i;
    return (unsigned short)((x + 0x7fffu + ((x >> 16) & 1u)) >> 16);
}

// ---------------- CSR build ----------------
__global__ void hist_k(const int* __restrict__ dst, const int* __restrict__ et,
                       int* __restrict__ cnt, int* __restrict__ rank, int ne) {
    int e = blockIdx.x * 256 + threadIdx.x;
    if (e < ne) rank[e] = atomicAdd(&cnt[dst[e] * RR + et[e]], 1);
}
__global__ void scan1_k(const int* __restrict__ cnt, int* __restrict__ bsum, int n) {
    __shared__ int sh[256];
    int base = blockIdx.x << 10;
    int s = 0;
    for (int i = threadIdx.x; i < 1024; i += 256) { int idx = base + i; if (idx < n) s += cnt[idx]; }
    sh[threadIdx.x] = s; __syncthreads();
    for (int off = 128; off > 0; off >>= 1) {
        if (threadIdx.x < off) sh[threadIdx.x] += sh[threadIdx.x + off];
        __syncthreads();
    }
    if (threadIdx.x == 0) bsum[blockIdx.x] = sh[0];
}
__global__ void scan2_k(int* __restrict__ bsum, int nb) {   // nb <= 1024
    __shared__ int sh[256];
    int t = threadIdx.x;
    int v[4]; int loc = 0;
#pragma unroll
    for (int i = 0; i < 4; ++i) { int idx = t * 4 + i; v[i] = (idx < nb) ? bsum[idx] : 0; loc += v[i]; }
    sh[t] = loc; __syncthreads();
    for (int off = 1; off < 256; off <<= 1) {
        int x = (t >= off) ? sh[t - off] : 0;
        __syncthreads();
        sh[t] += x;
        __syncthreads();
    }
    int ex = (t > 0) ? sh[t - 1] : 0;
#pragma unroll
    for (int i = 0; i < 4; ++i) { int idx = t * 4 + i; if (idx < nb) { int vv = v[i]; bsum[idx] = ex; ex += vv; } }
}
__global__ void scan3_k(const int* __restrict__ cnt, const int* __restrict__ boff,
                        int* __restrict__ ptr, int n, int total) {
    __shared__ int sh[256];
    int t = threadIdx.x;
    int base = (blockIdx.x << 10) + (t << 2);
    int v[4]; int loc = 0;
#pragma unroll
    for (int i = 0; i < 4; ++i) { int idx = base + i; v[i] = (idx < n) ? cnt[idx] : 0; loc += v[i]; }
    sh[t] = loc; __syncthreads();
    for (int off = 1; off < 256; off <<= 1) {
        int x = (t >= off) ? sh[t - off] : 0;
        __syncthreads();
        sh[t] += x;
        __syncthreads();
    }
    int ex = boff[blockIdx.x] + ((t > 0) ? sh[t - 1] : 0);
#pragma unroll
    for (int i = 0; i < 4; ++i) {
        int idx = base + i;
        if (idx < n) { ptr[idx] = ex; ex += v[i]; }
    }
    if (blockIdx.x == 0 && t == 0) ptr[n] = total;
}
// no atomics: pos = ptr[seg] + rank[e]; also zero the 16-int pad past E (it IS read
// by layer_k's clamped batch loads — workspace poison would be an OOB gather addr)
__global__ void scatter_k(const int* __restrict__ src, const int* __restrict__ dst,
                          const int* __restrict__ et, const int* __restrict__ rank,
                          const int* __restrict__ ptr, int* __restrict__ ssorted, int ne) {
    int e = blockIdx.x * 256 + threadIdx.x;
    if (e < ne) {
        int seg = dst[e] * RR + et[e];
        ssorted[ptr[seg] + rank[e]] = src[e];
    }
    if (blockIdx.x == 0 && threadIdx.x < 16) ssorted[ne + threadIdx.x] = 0;
}

// ---------------- fused prep: weights + features + fc transposes + BN fold ----------------
__global__ __launch_bounds__(256) void prep_all_k(
    const float* __restrict__ rel_w, const float* __restrict__ root_w,
    unsigned short* __restrict__ wall,
    const int* __restrict__ x, const float* __restrict__ embed,
    unsigned short* __restrict__ h, int n, int nhb,
    const float* __restrict__ fc0w, const float* __restrict__ fc1w,
    float* __restrict__ w0t, float* __restrict__ w1t,
    const float* __restrict__ conv_b,
    const float* __restrict__ bn_g, const float* __restrict__ bn_b,
    const float* __restrict__ bn_m, const float* __restrict__ bn_v,
    float* __restrict__ AB)
{
    __shared__ unsigned short T[128][130];
    int b = blockIdx.x;
    int t = threadIdx.x;
    if (b < 24) {
        int l = b >> 3, kb = b & 7;
        const float* src = (kb < RR) ? rel_w + ((size_t)(l * RR + kb) << 14)
                                     : root_w + ((size_t)l << 14);
        for (int c = t; c < 4096; c += 256) {
            float4 f = *(const float4*)(src + (c << 2));
            int i = c >> 5, o = (c & 31) << 2;
            T[i][o] = f2b(f.x); T[i][o+1] = f2b(f.y); T[i][o+2] = f2b(f.z); T[i][o+3] = f2b(f.w);
        }
        __syncthreads();
        unsigned short* dst = wall + ((size_t)b << 14);
        for (int c = t; c < 2048; c += 256) {
            int frag = c >> 6;
            int lane = c & 63;
            int ks = frag >> 3, nt = frag & 7;
            int o = (nt << 4) + (lane & 15);
            int ib = (ks << 5) + ((lane >> 4) << 3);
            uint4 o4;
            o4.x = (unsigned)T[ib+0][o] | ((unsigned)T[ib+1][o] << 16);
            o4.y = (unsigned)T[ib+2][o] | ((unsigned)T[ib+3][o] << 16);
            o4.z = (unsigned)T[ib+4][o] | ((unsigned)T[ib+5][o] << 16);
            o4.w = (unsigned)T[ib+6][o] | ((unsigned)T[ib+7][o] << 16);
            *(uint4*)(dst + (c << 3)) = o4;
        }
    } else if (b < 24 + nhb) {
        int i = (b - 24) * 256 + t;
        if (i < n * 16) {
            int node = i >> 4, c8 = (i & 15) << 3;
            const float* e = embed + ((size_t)x[node] << 7) + c8;
            float4 f0 = *(const float4*)e;
            float4 f1 = *(const float4*)(e + 4);
            uint4 o4;
            o4.x = (unsigned)f2b(f0.x) | ((unsigned)f2b(f0.y) << 16);
            o4.y = (unsigned)f2b(f0.z) | ((unsigned)f2b(f0.w) << 16);
            o4.z = (unsigned)f2b(f1.x) | ((unsigned)f2b(f1.y) << 16);
            o4.w = (unsigned)f2b(f1.z) | ((unsigned)f2b(f1.w) << 16);
            *(uint4*)(h + ((size_t)node << 7) + c8) = o4;
        }
    } else if (b < 24 + nhb + 256) {
        int idx = ((b - 24 - nhb) << 8) + t;
        int o = idx & 255, i = idx >> 8;
        w0t[idx] = fc0w[o * 256 + i];
    } else if (b < 24 + nhb + 384) {
        int idx = ((b - 24 - nhb - 256) << 8) + t;
        int o = idx & 127, i = idx >> 7;
        w1t[idx] = fc1w[o * 256 + i];
    } else {
        for (int q = t; q < 384; q += 256) {
            int l = q >> 7, j = q & 127;
            float A = 1.f, Bv = conv_b[(l << 7) + j];
            if (l < 2) {
                float sc = bn_g[(l << 7) + j] * rsqrtf(bn_v[(l << 7) + j] + EPSBN);
                A = sc;
                Bv = Bv * sc + (bn_b[(l << 7) + j] - bn_m[(l << 7) + j] * sc);
            }
            AB[(l << 8) + j] = A;
            AB[(l << 8) + 128 + j] = Bv;
        }
    }
}

#define PAIRF(pw) ((f32x2){uhi2f((pw) << 16), uhi2f((pw) & 0xffff0000u)})
#define ACCP(b, u) { av2[(b)+0] += PAIRF((u).x); av2[(b)+1] += PAIRF((u).y); \
                     av2[(b)+2] += PAIRF((u).z); av2[(b)+3] += PAIRF((u).w); }
#define ACCW(b, u, wgt) { av2[(b)+0] += (f32x2){wgt,wgt} * PAIRF((u).x); \
                          av2[(b)+1] += (f32x2){wgt,wgt} * PAIRF((u).y); \
                          av2[(b)+2] += (f32x2){wgt,wgt} * PAIRF((u).z); \
                          av2[(b)+3] += (f32x2){wgt,wgt} * PAIRF((u).w); }
#define GATH(s) { const unsigned short* hp = h_in + ((size_t)(s) << 7) + (quad << 3); \
                  uint4 u0 = *(const uint4*)(hp);       uint4 u1 = *(const uint4*)(hp + 32); \
                  uint4 u2 = *(const uint4*)(hp + 64);  uint4 u3 = *(const uint4*)(hp + 96); \
                  ACCP(0, u0); ACCP(4, u1); ACCP(8, u2); ACCP(12, u3); }
#define LOADROW(a, b, c, d, s) { const unsigned short* hp = h_in + ((size_t)(s) << 7) + (quad << 3); \
                  (a) = *(const uint4*)(hp);      (b) = *(const uint4*)(hp + 32); \
                  (c) = *(const uint4*)(hp + 64); (d) = *(const uint4*)(hp + 96); }

// ---------------- fused RGCN layer: unconditional batched staging ----------------
// 16 flat uint4 locals loaded UNCONDITIONALLY (indices clamped to last valid edge;
// dup addresses hit L1) -> register-allocated, 16 loads in flight per phase.
// Accumulation predicated by {0,1} weights via packed FMA (same op count as add).
__global__ __launch_bounds__(256, 3) void layer_k(
    const unsigned short* __restrict__ h_in,   // bf16 [N][128]
    unsigned short* __restrict__ h_out,        // bf16 [nout][128]
    const unsigned short* __restrict__ wfrag,  // bf16 [8][32][512]
    const float* __restrict__ AB,              // [2][128] scale,shift
    const int* __restrict__ seg_ptr, const int* __restrict__ src_sorted,
    const int* __restrict__ list_a, const int* __restrict__ list_b, int listB,
    int nout, int bnrelu)
{
    const int tid  = threadIdx.x;
    const int wave = tid >> 6;
    const int lane = tid & 63;
    const int n16  = lane & 15;
    const int quad = lane >> 4;
    const int row0 = blockIdx.x << 6;
    const int gidx = row0 + (wave << 4) + n16;   // output row
    const bool valid = gidx < nout;
    int gnode = 0;
    if (valid) {
        gnode = list_a ? (gidx < listB ? list_a[gidx] : list_b[gidx - listB]) : gidx;
    }

    int p[8];
    {
        int b = valid ? gnode * RR : 0;
#pragma unroll
        for (int i = 0; i < 8; ++i) p[i] = seg_ptr[b + i];
    }

    f32x4 acc[8];
#pragma unroll
    for (int i = 0; i < 8; ++i) acc[i] = (f32x4){0.f, 0.f, 0.f, 0.f};

    const unsigned short* wl = wfrag + (lane << 3);

#pragma unroll
    for (int kb = 0; kb < 8; ++kb) {
        f32x2 av2[16];
#pragma unroll
        for (int i = 0; i < 16; ++i) av2[i] = (f32x2){0.f, 0.f};
        float scale = 1.f;
        if (kb < RR) {
            int e0 = p[kb], e1 = p[kb + 1];
            int cnt = valid ? (e1 - e0) : 0;
            if (cnt > 0) scale = __builtin_amdgcn_rcpf((float)cnt);
            int cm = cnt - 1; if (cm < 0) cm = 0;
            int o1 = cm < 1 ? cm : 1;
            int o2 = cm < 2 ? cm : 2;
            int o3 = cm < 3 ? cm : 3;
            // index loads (src_sorted zero-padded 16 ints past E)
            int s0 = src_sorted[e0];
            int s1 = src_sorted[e0 + o1];
            int s2 = src_sorted[e0 + o2];
            int s3 = src_sorted[e0 + o3];
            // ---- unconditional batched load region: 16 loads in flight ----
            uint4 a0, a1, a2, a3, b0, b1, b2, b3, c0, c1, c2, c3, d0, d1, d2, d3;
            LOADROW(a0, a1, a2, a3, s0);
            LOADROW(b0, b1, b2, b3, s1);
            LOADROW(c0, c1, c2, c3, s2);
            LOADROW(d0, d1, d2, d3, s3);
            // ---- weighted accumulate ({0,1} predication) ----
            float q0 = cnt > 0 ? 1.f : 0.f;
            float q1 = cnt > 1 ? 1.f : 0.f;
            float q2 = cnt > 2 ? 1.f : 0.f;
            float q3 = cnt > 3 ? 1.f : 0.f;
            ACCW(0, a0, q0); ACCW(4, a1, q0); ACCW(8, a2, q0); ACCW(12, a3, q0);
            ACCW(0, b0, q1); ACCW(4, b1, q1); ACCW(8, b2, q1); ACCW(12, b3, q1);
            ACCW(0, c0, q2); ACCW(4, c1, q2); ACCW(8, c2, q2); ACCW(12, c3, q2);
            ACCW(0, d0, q3); ACCW(4, d1, q3); ACCW(8, d2, q3); ACCW(12, d3, q3);
            for (int e = e0 + 4; e < e0 + cnt; ++e) {
                int s = src_sorted[e];
                GATH(s);
            }
        } else {
            if (valid) GATH(gnode);
        }
        // convert to bf16 A-fragments
        uint4 au[4];
#pragma unroll
        for (int ks = 0; ks < 4; ++ks) {
            unsigned pw[4];
#pragma unroll
            for (int m = 0; m < 4; ++m) {
                f32x2 q = av2[(ks << 2) + m] * scale;
                __hip_bfloat162 b2 = __float22bfloat162_rn(make_float2(q.x, q.y));
                unsigned uu; __builtin_memcpy(&uu, &b2, 4);
                pw[m] = uu;
            }
            au[ks].x = pw[0]; au[ks].y = pw[1]; au[ks].z = pw[2]; au[ks].w = pw[3];
        }
        // MFMA, B-fragments from global (L2-resident 32KB)
        const unsigned short* wk = wl + (kb << 14);
#pragma unroll
        for (int ks = 0; ks < 4; ++ks) {
            bf16x8 af;
            __builtin_memcpy(&af, &au[ks], 16);
#pragma unroll
            for (int nt = 0; nt < 8; ++nt) {
                bf16x8 bfr = *(const bf16x8*)(wk + (((ks << 3) + nt) << 9));
                acc[nt] = __builtin_amdgcn_mfma_f32_16x16x32_bf16(af, bfr, acc[nt], 0, 0, 0);
            }
        }
    }

    // epilogue: v = acc*A + B (BN+bias folded), ReLU, store bf16
    // C/D layout: col = lane&15, row = (lane>>4)*4 + reg
#pragma unroll
    for (int nt = 0; nt < 8; ++nt) {
        int j = (nt << 4) + n16;
        float Aj = AB[j];
        float Bj = AB[128 + j];
#pragma unroll
        for (int r = 0; r < 4; ++r) {
            int orow = row0 + (wave << 4) + (quad << 2) + r;
            if (orow < nout) {
                float v = acc[nt][r] * Aj + Bj;
                if (bnrelu) v = fmaxf(v, 0.f);
                h_out[((size_t)orow << 7) + j] = f2b(v);
            }
        }
    }
}

// ---------------- MLP head: 16 rows/block; transposed weights, coalesced ----------------
__global__ __launch_bounds__(256) void mlp_k(
    const unsigned short* __restrict__ hC,     // compact [2B][128]
    const float* __restrict__ w0t, const float* __restrict__ bb0,   // w0t [256 in][256 out]
    const float* __restrict__ w1t, const float* __restrict__ bb1,   // w1t [256 in][128 out]
    const float* __restrict__ w2, const float* __restrict__ bb2,
    float* __restrict__ out, int Bn)
{
    __shared__ __attribute__((aligned(16))) float g0[16][256];
    __shared__ __attribute__((aligned(16))) float g1[16][256];
    __shared__ float lg[16][4];
    int t = threadIdx.x;
    {
        int row = t >> 4;
        int cseg = (t & 15) << 4;
        int gr = (blockIdx.x << 4) + row;
        int gc = (gr < Bn) ? gr : 0;
        const unsigned short* sp = (cseg < 128) ? (hC + ((size_t)gc << 7) + cseg)
                                                : (hC + ((size_t)(Bn + gc) << 7) + (cseg - 128));
#pragma unroll
        for (int c8 = 0; c8 < 2; ++c8) {
            uint4 v = *(const uint4*)(sp + (c8 << 3));
            int base = cseg + (c8 << 3);
            g0[row][base+0] = uhi2f(v.x << 16); g0[row][base+1] = uhi2f(v.x & 0xffff0000u);
            g0[row][base+2] = uhi2f(v.y << 16); g0[row][base+3] = uhi2f(v.y & 0xffff0000u);
            g0[row][base+4] = uhi2f(v.z << 16); g0[row][base+5] = uhi2f(v.z & 0xffff0000u);
            g0[row][base+6] = uhi2f(v.w << 16); g0[row][base+7] = uhi2f(v.w & 0xffff0000u);
        }
    }
    __syncthreads();
    {   // fc0
        float acc[16];
#pragma unroll
        for (int r = 0; r < 16; ++r) acc[r] = 0.f;
#pragma unroll 4
        for (int i = 0; i < 256; ++i) {
            float w = w0t[(i << 8) + t];
#pragma unroll
            for (int r = 0; r < 16; ++r) acc[r] += w * g0[r][i];
        }
        float bb = bb0[t];
#pragma unroll
        for (int r = 0; r < 16; ++r) g1[r][t] = fmaxf(acc[r] + bb, 0.f);
    }
    __syncthreads();
    {   // fc1
        int o = t & 127, rg = t >> 7;
        float acc[8];
#pragma unroll
        for (int r = 0; r < 8; ++r) acc[r] = 0.f;
#pragma unroll 4
        for (int i = 0; i < 256; ++i) {
            float w = w1t[(i << 7) + o];
#pragma unroll
            for (int r = 0; r < 8; ++r) acc[r] += w * g1[(rg << 3) + r][i];
        }
        float bb = bb1[o];
#pragma unroll
        for (int r = 0; r < 8; ++r) g0[(rg << 3) + r][o] = fmaxf(acc[r] + bb, 0.f);
    }
    __syncthreads();
    if (t < 48) {   // fc2
        int row = t / 3, cls = t - row * 3;
        const float* wr = w2 + (cls << 7);
        float a = 0.f;
        for (int i = 0; i < 128; i += 4) {
            float4 w = *(const float4*)(wr + i);
            float4 g = *(const float4*)&g0[row][i];
            a += w.x * g.x + w.y * g.y + w.z * g.z + w.w * g.w;
        }
        lg[row][cls] = a + bb2[cls];
    }
    __syncthreads();
    if (t < 16) {   // log_softmax + store
        int gr = (blockIdx.x << 4) + t;
        if (gr < Bn) {
            float l0 = lg[t][0], l1 = lg[t][1], l2 = lg[t][2];
            float m = fmaxf(l0, fmaxf(l1, l2));
            float lse = m + logf(expf(l0 - m) + expf(l1 - m) + expf(l2 - m));
            out[gr * 3 + 0] = l0 - lse;
            out[gr * 3 + 1] = l1 - lse;
            out[gr * 3 + 2] = l2 - lse;
        }
    }
}

extern "C" void kernel_launch(void* const* d_in, const int* in_sizes, int n_in,
                              void* d_out, int out_size, void* d_ws, size_t ws_size,
                              hipStream_t stream) {
    const int*   x      = (const int*)d_in[0];
    const int*   eidx   = (const int*)d_in[1];   // [2, E]
    const int*   etype  = (const int*)d_in[2];
    const int*   home   = (const int*)d_in[3];
    const int*   away   = (const int*)d_in[4];
    const float* embed  = (const float*)d_in[5];
    const float* rel_w  = (const float*)d_in[6];
    const float* root_w = (const float*)d_in[7];
    const float* conv_b = (const float*)d_in[8];
    const float* bn_g   = (const float*)d_in[9];
    const float* bn_b   = (const float*)d_in[10];
    const float* bn_m   = (const float*)d_in[11];
    const float* bn_v   = (const float*)d_in[12];
    const float* fc0w   = (const float*)d_in[13];
    const float* fc0b   = (const float*)d_in[14];
    const float* fc1w   = (const float*)d_in[15];
    const float* fc1b   = (const float*)d_in[16];
    const float* fc2w   = (const float*)d_in[17];
    const float* fc2b   = (const float*)d_in[18];
    float* out = (float*)d_out;

    const int N_ = in_sizes[0];
    const int E_ = in_sizes[2];
    const int B_ = in_sizes[3];
    const int NS = N_ * RR;

    char* ws = (char*)d_ws;
    auto alloc = [&](size_t bytes) -> char* {
        char* p = ws;
        ws += (bytes + 255) & ~(size_t)255;
        return p;
    };
    int* ptr         = (int*)alloc((size_t)(NS + 1) * 4);
    int* cursor      = (int*)alloc((size_t)NS * 4);
    int* bsum        = (int*)alloc(4096);
    int* rank        = (int*)alloc((size_t)E_ * 4);
    int* src_sorted  = (int*)alloc((size_t)(E_ + 16) * 4);   // zero-padded tail
    unsigned short* wall = (unsigned short*)alloc((size_t)3 * 8 * 16384 * 2);
    unsigned short* hA   = (unsigned short*)alloc((size_t)N_ * 128 * 2);
    unsigned short* hB   = (unsigned short*)alloc((size_t)N_ * 128 * 2);
    unsigned short* hC   = (unsigned short*)alloc((size_t)2 * B_ * 128 * 2);
    float* AB        = (float*)alloc(3 * 256 * 4);
    float* w0t       = (float*)alloc(65536 * 4);
    float* w1t       = (float*)alloc(32768 * 4);

    const int nb = (NS + 1023) / 1024;
    const int nhb = (N_ * 16 + 255) / 256;

    // CSR build (segments constant across layers)
    (void)hipMemsetAsync(cursor, 0, (size_t)NS * 4, stream);
    hist_k<<<(E_ + 255) / 256, 256, 0, stream>>>(eidx + E_, etype, cursor, rank, E_);
    scan1_k<<<nb, 256, 0, stream>>>(cursor, bsum, NS);
    scan2_k<<<1, 256, 0, stream>>>(bsum, nb);
    scan3_k<<<nb, 256, 0, stream>>>(cursor, bsum, ptr, NS, E_);
    scatter_k<<<(E_ + 255) / 256, 256, 0, stream>>>(eidx, eidx + E_, etype, rank, ptr,
                                                    src_sorted, E_);

    // fused prep: wall + hA + w0t/w1t transposes + AB
    prep_all_k<<<24 + nhb + 384 + 1, 256, 0, stream>>>(
        rel_w, root_w, wall, x, embed, hA, N_, nhb,
        fc0w, fc1w, w0t, w1t, conv_b, bn_g, bn_b, bn_m, bn_v, AB);

    const int lgrid = (N_ + 63) / 64;
    layer_k<<<lgrid, 256, 0, stream>>>(hA, hB, wall + 0 * 8 * 16384, AB + 0,
                                       ptr, src_sorted, nullptr, nullptr, 0, N_, 1);
    layer_k<<<lgrid, 256, 0, stream>>>(hB, hA, wall + 1 * 8 * 16384, AB + 256,
                                       ptr, src_sorted, nullptr, nullptr, 0, N_, 1);
    // layer 3: only home|away rows, compact output
    const int n3 = 2 * B_;
    layer_k<<<(n3 + 63) / 64, 256, 0, stream>>>(hA, hC, wall + 2 * 8 * 16384, AB + 512,
                                                ptr, src_sorted, home, away, B_, n3, 0);

    mlp_k<<<(B_ + 15) / 16, 256, 0, stream>>>(hC, w0t, fc0b, w1t, fc1b,
                                              fc2w, fc2b, out, B_);
}

// Round 10
// 632.993 us; speedup vs baseline: 1.4008x; 1.0841x over previous
//
#include <hip/hip_runtime.h>
#include <hip/hip_bf16.h>

#define RR 7
#define EPSBN 1e-5f

typedef __attribute__((ext_vector_type(8))) __bf16 bf16x8;
typedef __attribute__((ext_vector_type(4))) float f32x4;
typedef __attribute__((ext_vector_type(2))) float f32x2;

__device__ __forceinline__ float uhi2f(unsigned int u) {
    union { unsigned int i; float f; } c; c.i = u; return c.f;
}
__device__ __forceinline__ unsigned short f2b(float f) {
    union { float f; unsigned int i; } c; c.f = f;
    unsigned int x = c.i;
    return (unsigned short)((x + 0x7fffu + ((x >> 16) & 1u)) >> 16);
}

// ---------------- CSR build ----------------
__global__ void hist_k(const int* __restrict__ dst, const int* __restrict__ et,
                       int* __restrict__ cnt, int* __restrict__ rank, int ne) {
    int e = blockIdx.x * 256 + threadIdx.x;
    if (e < ne) rank[e] = atomicAdd(&cnt[dst[e] * RR + et[e]], 1);
}
__global__ void scan1_k(const int* __restrict__ cnt, int* __restrict__ bsum, int n) {
    __shared__ int sh[256];
    int base = blockIdx.x << 10;
    int s = 0;
    for (int i = threadIdx.x; i < 1024; i += 256) { int idx = base + i; if (idx < n) s += cnt[idx]; }
    sh[threadIdx.x] = s; __syncthreads();
    for (int off = 128; off > 0; off >>= 1) {
        if (threadIdx.x < off) sh[threadIdx.x] += sh[threadIdx.x + off];
        __syncthreads();
    }
    if (threadIdx.x == 0) bsum[blockIdx.x] = sh[0];
}
__global__ void scan2_k(int* __restrict__ bsum, int nb) {   // nb <= 1024
    __shared__ int sh[256];
    int t = threadIdx.x;
    int v[4]; int loc = 0;
#pragma unroll
    for (int i = 0; i < 4; ++i) { int idx = t * 4 + i; v[i] = (idx < nb) ? bsum[idx] : 0; loc += v[i]; }
    sh[t] = loc; __syncthreads();
    for (int off = 1; off < 256; off <<= 1) {
        int x = (t >= off) ? sh[t - off] : 0;
        __syncthreads();
        sh[t] += x;
        __syncthreads();
    }
    int ex = (t > 0) ? sh[t - 1] : 0;
#pragma unroll
    for (int i = 0; i < 4; ++i) { int idx = t * 4 + i; if (idx < nb) { int vv = v[i]; bsum[idx] = ex; ex += vv; } }
}
__global__ void scan3_k(const int* __restrict__ cnt, const int* __restrict__ boff,
                        int* __restrict__ ptr, int n, int total) {
    __shared__ int sh[256];
    int t = threadIdx.x;
    int base = (blockIdx.x << 10) + (t << 2);
    int v[4]; int loc = 0;
#pragma unroll
    for (int i = 0; i < 4; ++i) { int idx = base + i; v[i] = (idx < n) ? cnt[idx] : 0; loc += v[i]; }
    sh[t] = loc; __syncthreads();
    for (int off = 1; off < 256; off <<= 1) {
        int x = (t >= off) ? sh[t - off] : 0;
        __syncthreads();
        sh[t] += x;
        __syncthreads();
    }
    int ex = boff[blockIdx.x] + ((t > 0) ? sh[t - 1] : 0);
#pragma unroll
    for (int i = 0; i < 4; ++i) {
        int idx = base + i;
        if (idx < n) { ptr[idx] = ex; ex += v[i]; }
    }
    if (blockIdx.x == 0 && t == 0) ptr[n] = total;
}
__global__ void scatter_k(const int* __restrict__ src, const int* __restrict__ dst,
                          const int* __restrict__ et, const int* __restrict__ rank,
                          const int* __restrict__ ptr, int* __restrict__ ssorted, int ne) {
    int e = blockIdx.x * 256 + threadIdx.x;
    if (e < ne) {
        int seg = dst[e] * RR + et[e];
        ssorted[ptr[seg] + rank[e]] = src[e];
    }
    if (blockIdx.x == 0 && threadIdx.x < 16) ssorted[ne + threadIdx.x] = 0;
}

// ---------------- frontier for the middle layer ----------------
// mark in-neighbors of home|away (plus the nodes themselves, needed for the l=2 root term)
__global__ void mark_k(const int* __restrict__ home, const int* __restrict__ away,
                       const int* __restrict__ ptr, const int* __restrict__ ssorted,
                       int* __restrict__ mark, int Bn) {
    int i = blockIdx.x * 256 + threadIdx.x;
    if (i >= 2 * Bn) return;
    int node = (i < Bn) ? home[i] : away[i - Bn];
    mark[node] = 1;
    int e0 = ptr[node * RR], e1 = ptr[node * RR + RR];
    for (int e = e0; e < e1; ++e) mark[ssorted[e]] = 1;
}
__global__ void compact_k(const int* __restrict__ mark, int* __restrict__ list,
                          int* __restrict__ count, int n) {
    int i = blockIdx.x * 256 + threadIdx.x;
    if (i < n && mark[i]) { int p = atomicAdd(count, 1); list[p] = i; }
}

// ---------------- fused prep: weights + features + fc transposes + BN fold ----------------
__global__ __launch_bounds__(256) void prep_all_k(
    const float* __restrict__ rel_w, const float* __restrict__ root_w,
    unsigned short* __restrict__ wall,
    const int* __restrict__ x, const float* __restrict__ embed,
    unsigned short* __restrict__ h, int n, int nhb,
    const float* __restrict__ fc0w, const float* __restrict__ fc1w,
    float* __restrict__ w0t, float* __restrict__ w1t,
    const float* __restrict__ conv_b,
    const float* __restrict__ bn_g, const float* __restrict__ bn_b,
    const float* __restrict__ bn_m, const float* __restrict__ bn_v,
    float* __restrict__ AB)
{
    __shared__ unsigned short T[128][130];
    int b = blockIdx.x;
    int t = threadIdx.x;
    if (b < 24) {
        int l = b >> 3, kb = b & 7;
        const float* src = (kb < RR) ? rel_w + ((size_t)(l * RR + kb) << 14)
                                     : root_w + ((size_t)l << 14);
        for (int c = t; c < 4096; c += 256) {
            float4 f = *(const float4*)(src + (c << 2));
            int i = c >> 5, o = (c & 31) << 2;
            T[i][o] = f2b(f.x); T[i][o+1] = f2b(f.y); T[i][o+2] = f2b(f.z); T[i][o+3] = f2b(f.w);
        }
        __syncthreads();
        unsigned short* dst = wall + ((size_t)b << 14);
        for (int c = t; c < 2048; c += 256) {
            int frag = c >> 6;
            int lane = c & 63;
            int ks = frag >> 3, nt = frag & 7;
            int o = (nt << 4) + (lane & 15);
            int ib = (ks << 5) + ((lane >> 4) << 3);
            uint4 o4;
            o4.x = (unsigned)T[ib+0][o] | ((unsigned)T[ib+1][o] << 16);
            o4.y = (unsigned)T[ib+2][o] | ((unsigned)T[ib+3][o] << 16);
            o4.z = (unsigned)T[ib+4][o] | ((unsigned)T[ib+5][o] << 16);
            o4.w = (unsigned)T[ib+6][o] | ((unsigned)T[ib+7][o] << 16);
            *(uint4*)(dst + (c << 3)) = o4;
        }
    } else if (b < 24 + nhb) {
        int i = (b - 24) * 256 + t;
        if (i < n * 16) {
            int node = i >> 4, c8 = (i & 15) << 3;
            const float* e = embed + ((size_t)x[node] << 7) + c8;
            float4 f0 = *(const float4*)e;
            float4 f1 = *(const float4*)(e + 4);
            uint4 o4;
            o4.x = (unsigned)f2b(f0.x) | ((unsigned)f2b(f0.y) << 16);
            o4.y = (unsigned)f2b(f0.z) | ((unsigned)f2b(f0.w) << 16);
            o4.z = (unsigned)f2b(f1.x) | ((unsigned)f2b(f1.y) << 16);
            o4.w = (unsigned)f2b(f1.z) | ((unsigned)f2b(f1.w) << 16);
            *(uint4*)(h + ((size_t)node << 7) + c8) = o4;
        }
    } else if (b < 24 + nhb + 256) {
        int idx = ((b - 24 - nhb) << 8) + t;
        int o = idx & 255, i = idx >> 8;
        w0t[idx] = fc0w[o * 256 + i];
    } else if (b < 24 + nhb + 384) {
        int idx = ((b - 24 - nhb - 256) << 8) + t;
        int o = idx & 127, i = idx >> 7;
        w1t[idx] = fc1w[o * 256 + i];
    } else {
        for (int q = t; q < 384; q += 256) {
            int l = q >> 7, j = q & 127;
            float A = 1.f, Bv = conv_b[(l << 7) + j];
            if (l < 2) {
                float sc = bn_g[(l << 7) + j] * rsqrtf(bn_v[(l << 7) + j] + EPSBN);
                A = sc;
                Bv = Bv * sc + (bn_b[(l << 7) + j] - bn_m[(l << 7) + j] * sc);
            }
            AB[(l << 8) + j] = A;
            AB[(l << 8) + 128 + j] = Bv;
        }
    }
}

#define PAIRF(pw) ((f32x2){uhi2f((pw) << 16), uhi2f((pw) & 0xffff0000u)})
#define ACCP(b, u) { av2[(b)+0] += PAIRF((u).x); av2[(b)+1] += PAIRF((u).y); \
                     av2[(b)+2] += PAIRF((u).z); av2[(b)+3] += PAIRF((u).w); }
#define GATH(s) { const unsigned short* hp = h_in + ((size_t)(s) << 7) + (quad << 3); \
                  uint4 u0 = *(const uint4*)(hp);       uint4 u1 = *(const uint4*)(hp + 32); \
                  uint4 u2 = *(const uint4*)(hp + 64);  uint4 u3 = *(const uint4*)(hp + 96); \
                  ACCP(0, u0); ACCP(4, u1); ACCP(8, u2); ACCP(12, u3); }

// ---------------- fused RGCN layer (round-6 structure: best measured) ----------------
// mode: list==nullptr -> rows are node ids 0..nout-1, compact output.
//       list!=nullptr, by_node=0 -> rows are list positions, compact output (l=2 head rows).
//       list!=nullptr, by_node=1 -> rows are list positions, output written at node id
//                                   (frontier middle layer). nout_dev overrides nout.
__global__ __launch_bounds__(256, 4) void layer_k(
    const unsigned short* __restrict__ h_in,   // bf16 [N][128]
    unsigned short* __restrict__ h_out,
    const unsigned short* __restrict__ wfrag,  // bf16 [8][32][512]
    const float* __restrict__ AB,              // [2][128] scale,shift
    const int* __restrict__ seg_ptr, const int* __restrict__ src_sorted,
    const int* __restrict__ list_a, const int* __restrict__ list_b, int listB,
    const int* __restrict__ nout_dev,
    int nout, int bnrelu, int by_node)
{
    const int tid  = threadIdx.x;
    const int wave = tid >> 6;
    const int lane = tid & 63;
    const int n16  = lane & 15;
    const int quad = lane >> 4;
    const int row0 = blockIdx.x << 6;
    if (nout_dev) nout = *nout_dev;
    if (row0 >= nout) return;
    const int gidx = row0 + (wave << 4) + n16;   // row index
    const bool valid = gidx < nout;
    int gnode = 0;
    if (valid) {
        gnode = list_a ? (gidx < listB ? list_a[gidx] : list_b[gidx - listB]) : gidx;
    }

    int p[8];
    {
        int b = valid ? gnode * RR : 0;
#pragma unroll
        for (int i = 0; i < 8; ++i) p[i] = seg_ptr[b + i];
    }

    f32x4 acc[8];
#pragma unroll
    for (int i = 0; i < 8; ++i) acc[i] = (f32x4){0.f, 0.f, 0.f, 0.f};

    // preload first relation's src indices (src_sorted zero-padded >=16 ints)
    int sv0, sv1, sv2, sv3;
    { int e0 = p[0]; sv0 = src_sorted[e0]; sv1 = src_sorted[e0+1];
      sv2 = src_sorted[e0+2]; sv3 = src_sorted[e0+3]; }

    const unsigned short* wl = wfrag + (lane << 3);

#pragma unroll
    for (int kb = 0; kb < 8; ++kb) {
        f32x2 av2[16];
#pragma unroll
        for (int i = 0; i < 16; ++i) av2[i] = (f32x2){0.f, 0.f};
        float scale = 1.f;
        int nv0 = 0, nv1 = 0, nv2 = 0, nv3 = 0;
        if (kb < RR) {
            // prefetch next relation's indices early (independent of this gather)
            if (kb < RR - 1) {
                int en = p[kb + 1];
                nv0 = src_sorted[en]; nv1 = src_sorted[en+1];
                nv2 = src_sorted[en+2]; nv3 = src_sorted[en+3];
            }
            if (valid) {
                int e0 = p[kb], e1 = p[kb + 1];
                int cnt = e1 - e0;
                if (cnt > 0) scale = __builtin_amdgcn_rcpf((float)cnt);
                if (cnt > 0) GATH(sv0);
                if (cnt > 1) GATH(sv1);
                if (cnt > 2) GATH(sv2);
                if (cnt > 3) GATH(sv3);
                for (int e = e0 + 4; e < e1; ++e) {
                    int s = src_sorted[e];
                    GATH(s);
                }
            }
        } else {
            if (valid) GATH(gnode);
        }
        // convert to bf16 A-fragments
        uint4 au[4];
#pragma unroll
        for (int ks = 0; ks < 4; ++ks) {
            unsigned pw[4];
#pragma unroll
            for (int m = 0; m < 4; ++m) {
                f32x2 q = av2[(ks << 2) + m] * scale;
                __hip_bfloat162 b2 = __float22bfloat162_rn(make_float2(q.x, q.y));
                unsigned uu; __builtin_memcpy(&uu, &b2, 4);
                pw[m] = uu;
            }
            au[ks].x = pw[0]; au[ks].y = pw[1]; au[ks].z = pw[2]; au[ks].w = pw[3];
        }
        // MFMA, B-fragments from global (L2-resident 32KB)
        const unsigned short* wk = wl + (kb << 14);
#pragma unroll
        for (int ks = 0; ks < 4; ++ks) {
            bf16x8 af;
            __builtin_memcpy(&af, &au[ks], 16);
#pragma unroll
            for (int nt = 0; nt < 8; ++nt) {
                bf16x8 bfr = *(const bf16x8*)(wk + (((ks << 3) + nt) << 9));
                acc[nt] = __builtin_amdgcn_mfma_f32_16x16x32_bf16(af, bfr, acc[nt], 0, 0, 0);
            }
        }
        sv0 = nv0; sv1 = nv1; sv2 = nv2; sv3 = nv3;
    }

    // epilogue: v = acc*A + B (BN+bias folded), ReLU, store bf16
    // C/D layout: col = lane&15, row = (lane>>4)*4 + reg
    int orow[4];
#pragma unroll
    for (int r = 0; r < 4; ++r) {
        int ri = row0 + (wave << 4) + (quad << 2) + r;
        if (ri < nout) {
            orow[r] = by_node ? (ri < listB ? list_a[ri] : list_b[ri - listB]) : ri;
        } else orow[r] = -1;
    }
#pragma unroll
    for (int nt = 0; nt < 8; ++nt) {
        int j = (nt << 4) + n16;
        float Aj = AB[j];
        float Bj = AB[128 + j];
#pragma unroll
        for (int r = 0; r < 4; ++r) {
            if (orow[r] >= 0) {
                float v = acc[nt][r] * Aj + Bj;
                if (bnrelu) v = fmaxf(v, 0.f);
                h_out[((size_t)orow[r] << 7) + j] = f2b(v);
            }
        }
    }
}

// ---------------- MLP head: 16 rows/block; transposed weights, coalesced ----------------
__global__ __launch_bounds__(256) void mlp_k(
    const unsigned short* __restrict__ hC,     // compact [2B][128]
    const float* __restrict__ w0t, const float* __restrict__ bb0,
    const float* __restrict__ w1t, const float* __restrict__ bb1,
    const float* __restrict__ w2, const float* __restrict__ bb2,
    float* __restrict__ out, int Bn)
{
    __shared__ __attribute__((aligned(16))) float g0[16][256];
    __shared__ __attribute__((aligned(16))) float g1[16][256];
    __shared__ float lg[16][4];
    int t = threadIdx.x;
    {
        int row = t >> 4;
        int cseg = (t & 15) << 4;
        int gr = (blockIdx.x << 4) + row;
        int gc = (gr < Bn) ? gr : 0;
        const unsigned short* sp = (cseg < 128) ? (hC + ((size_t)gc << 7) + cseg)
                                                : (hC + ((size_t)(Bn + gc) << 7) + (cseg - 128));
#pragma unroll
        for (int c8 = 0; c8 < 2; ++c8) {
            uint4 v = *(const uint4*)(sp + (c8 << 3));
            int base = cseg + (c8 << 3);
            g0[row][base+0] = uhi2f(v.x << 16); g0[row][base+1] = uhi2f(v.x & 0xffff0000u);
            g0[row][base+2] = uhi2f(v.y << 16); g0[row][base+3] = uhi2f(v.y & 0xffff0000u);
            g0[row][base+4] = uhi2f(v.z << 16); g0[row][base+5] = uhi2f(v.z & 0xffff0000u);
            g0[row][base+6] = uhi2f(v.w << 16); g0[row][base+7] = uhi2f(v.w & 0xffff0000u);
        }
    }
    __syncthreads();
    {   // fc0
        float acc[16];
#pragma unroll
        for (int r = 0; r < 16; ++r) acc[r] = 0.f;
#pragma unroll 4
        for (int i = 0; i < 256; ++i) {
            float w = w0t[(i << 8) + t];
#pragma unroll
            for (int r = 0; r < 16; ++r) acc[r] += w * g0[r][i];
        }
        float bb = bb0[t];
#pragma unroll
        for (int r = 0; r < 16; ++r) g1[r][t] = fmaxf(acc[r] + bb, 0.f);
    }
    __syncthreads();
    {   // fc1
        int o = t & 127, rg = t >> 7;
        float acc[8];
#pragma unroll
        for (int r = 0; r < 8; ++r) acc[r] = 0.f;
#pragma unroll 4
        for (int i = 0; i < 256; ++i) {
            float w = w1t[(i << 7) + o];
#pragma unroll
            for (int r = 0; r < 8; ++r) acc[r] += w * g1[(rg << 3) + r][i];
        }
        float bb = bb1[o];
#pragma unroll
        for (int r = 0; r < 8; ++r) g0[(rg << 3) + r][o] = fmaxf(acc[r] + bb, 0.f);
    }
    __syncthreads();
    if (t < 48) {   // fc2
        int row = t / 3, cls = t - row * 3;
        const float* wr = w2 + (cls << 7);
        float a = 0.f;
        for (int i = 0; i < 128; i += 4) {
            float4 w = *(const float4*)(wr + i);
            float4 g = *(const float4*)&g0[row][i];
            a += w.x * g.x + w.y * g.y + w.z * g.z + w.w * g.w;
        }
        lg[row][cls] = a + bb2[cls];
    }
    __syncthreads();
    if (t < 16) {   // log_softmax + store
        int gr = (blockIdx.x << 4) + t;
        if (gr < Bn) {
            float l0 = lg[t][0], l1 = lg[t][1], l2 = lg[t][2];
            float m = fmaxf(l0, fmaxf(l1, l2));
            float lse = m + logf(expf(l0 - m) + expf(l1 - m) + expf(l2 - m));
            out[gr * 3 + 0] = l0 - lse;
            out[gr * 3 + 1] = l1 - lse;
            out[gr * 3 + 2] = l2 - lse;
        }
    }
}

extern "C" void kernel_launch(void* const* d_in, const int* in_sizes, int n_in,
                              void* d_out, int out_size, void* d_ws, size_t ws_size,
                              hipStream_t stream) {
    const int*   x      = (const int*)d_in[0];
    const int*   eidx   = (const int*)d_in[1];   // [2, E]
    const int*   etype  = (const int*)d_in[2];
    const int*   home   = (const int*)d_in[3];
    const int*   away   = (const int*)d_in[4];
    const float* embed  = (const float*)d_in[5];
    const float* rel_w  = (const float*)d_in[6];
    const float* root_w = (const float*)d_in[7];
    const float* conv_b = (const float*)d_in[8];
    const float* bn_g   = (const float*)d_in[9];
    const float* bn_b   = (const float*)d_in[10];
    const float* bn_m   = (const float*)d_in[11];
    const float* bn_v   = (const float*)d_in[12];
    const float* fc0w   = (const float*)d_in[13];
    const float* fc0b   = (const float*)d_in[14];
    const float* fc1w   = (const float*)d_in[15];
    const float* fc1b   = (const float*)d_in[16];
    const float* fc2w   = (const float*)d_in[17];
    const float* fc2b   = (const float*)d_in[18];
    float* out = (float*)d_out;

    const int N_ = in_sizes[0];
    const int E_ = in_sizes[2];
    const int B_ = in_sizes[3];
    const int NS = N_ * RR;

    char* ws = (char*)d_ws;
    auto alloc = [&](size_t bytes) -> char* {
        char* p = ws;
        ws += (bytes + 255) & ~(size_t)255;
        return p;
    };
    int* ptr         = (int*)alloc((size_t)(NS + 1) * 4);
    int* cursor      = (int*)alloc((size_t)NS * 4);
    int* bsum        = (int*)alloc(4096);
    int* rank        = (int*)alloc((size_t)E_ * 4);
    int* src_sorted  = (int*)alloc((size_t)(E_ + 16) * 4);   // zero-padded tail
    int* mark        = (int*)alloc((size_t)(N_ + 1) * 4);    // mark[N] + count
    int* flist       = (int*)alloc((size_t)N_ * 4);
    unsigned short* wall = (unsigned short*)alloc((size_t)3 * 8 * 16384 * 2);
    unsigned short* hA   = (unsigned short*)alloc((size_t)N_ * 128 * 2);
    unsigned short* hB   = (unsigned short*)alloc((size_t)N_ * 128 * 2);
    unsigned short* hC   = (unsigned short*)alloc((size_t)2 * B_ * 128 * 2);
    float* AB        = (float*)alloc(3 * 256 * 4);
    float* w0t       = (float*)alloc(65536 * 4);
    float* w1t       = (float*)alloc(32768 * 4);
    int* fcount      = mark + N_;

    const int nb = (NS + 1023) / 1024;
    const int nhb = (N_ * 16 + 255) / 256;

    // CSR build (segments constant across layers)
    (void)hipMemsetAsync(cursor, 0, (size_t)NS * 4, stream);
    (void)hipMemsetAsync(mark, 0, (size_t)(N_ + 1) * 4, stream);
    hist_k<<<(E_ + 255) / 256, 256, 0, stream>>>(eidx + E_, etype, cursor, rank, E_);
    scan1_k<<<nb, 256, 0, stream>>>(cursor, bsum, NS);
    scan2_k<<<1, 256, 0, stream>>>(bsum, nb);
    scan3_k<<<nb, 256, 0, stream>>>(cursor, bsum, ptr, NS, E_);
    scatter_k<<<(E_ + 255) / 256, 256, 0, stream>>>(eidx, eidx + E_, etype, rank, ptr,
                                                    src_sorted, E_);

    // frontier for the middle layer: in-neighbors of home|away plus the nodes themselves
    mark_k<<<(2 * B_ + 255) / 256, 256, 0, stream>>>(home, away, ptr, src_sorted, mark, B_);
    compact_k<<<(N_ + 255) / 256, 256, 0, stream>>>(mark, flist, fcount, N_);

    // fused prep: wall + hA + w0t/w1t transposes + AB
    prep_all_k<<<24 + nhb + 384 + 1, 256, 0, stream>>>(
        rel_w, root_w, wall, x, embed, hA, N_, nhb,
        fc0w, fc1w, w0t, w1t, conv_b, bn_g, bn_b, bn_m, bn_v, AB);

    const int lgrid = (N_ + 63) / 64;
    // layer 0: all nodes
    layer_k<<<lgrid, 256, 0, stream>>>(hA, hB, wall + 0 * 8 * 16384, AB + 0,
                                       ptr, src_sorted, nullptr, nullptr, 0,
                                       nullptr, N_, 1, 0);
    // layer 1: frontier nodes only, output written by node id into hA
    layer_k<<<lgrid, 256, 0, stream>>>(hB, hA, wall + 1 * 8 * 16384, AB + 256,
                                       ptr, src_sorted, flist, flist, N_,
                                       fcount, N_, 1, 1);
    // layer 2: only home|away rows, compact output
    const int n3 = 2 * B_;
    layer_k<<<(n3 + 63) / 64, 256, 0, stream>>>(hA, hC, wall + 2 * 8 * 16384, AB + 512,
                                                ptr, src_sorted, home, away, B_,
                                                nullptr, n3, 0, 0);

    mlp_k<<<(B_ + 15) / 16, 256, 0, stream>>>(hC, w0t, fc0b, w1t, fc1b,
                                              fc2w, fc2b, out, B_);
}